// Round 1
// baseline (3367.509 us; speedup 1.0000x reference)
//
#include <hip/hip_runtime.h>
#include <math.h>

// Problem constants (B=1)
#define TCTX 4096
#define HEADS 16
#define CH 64
#define W3 3072        // 3 * 1024
#define BQ 64          // queries per block
#define BK 64          // keys per tile
#define LSTR 65        // LDS row stride (pad +1 to break bank conflicts)

// One block: 256 threads handle a 64-query tile for one head.
// Thread (r, j): r = tid>>2 (q-row 0..63), j = tid&3 (quarter 0..3).
// Each thread owns 16 S-columns (j*16..j*16+15) and 16 O-channels.
__global__ __launch_bounds__(256, 2) void attn_fused_kernel(
    const float* __restrict__ qkv,
    const float* __restrict__ q_gamma, const float* __restrict__ q_beta,
    const float* __restrict__ k_gamma, const float* __restrict__ k_beta,
    float* __restrict__ out)
{
    __shared__ float Qs[BQ * LSTR];
    __shared__ float Ks[BK * LSTR];
    __shared__ float Vs[BK * LSTR];
    __shared__ float Ps[BQ * LSTR];

    const int tid = threadIdx.x;
    const int h  = blockIdx.y;
    const int q0 = blockIdx.x * BQ;
    const int r  = tid >> 2;
    const int j  = tid & 3;

    const float scale = 0.35355339059327373f;  // 64^(-1/4)

    // ---- load Q tile (coalesced: 64-float contiguous runs) ----
    for (int i = 0; i < 16; ++i) {
        int idx = tid + i * 256;
        int rr = idx >> 6, cc = idx & 63;
        Qs[rr * LSTR + cc] = qkv[(size_t)(q0 + rr) * W3 + h * 192 + cc];
    }
    __syncthreads();

    // ---- LayerNorm Q rows (4 lanes per row, shuffle-reduce) ----
    {
        float s = 0.f, s2 = 0.f;
        for (int i = 0; i < 16; ++i) {
            float x = Qs[r * LSTR + j * 16 + i];
            s += x; s2 += x * x;
        }
        s  += __shfl_xor(s, 1);  s  += __shfl_xor(s, 2);
        s2 += __shfl_xor(s2, 1); s2 += __shfl_xor(s2, 2);
        float mu   = s * (1.f / 64.f);
        float var  = s2 * (1.f / 64.f) - mu * mu;
        float rsig = rsqrtf(var + 1e-6f);
        for (int i = 0; i < 16; ++i) {
            int c = j * 16 + i;
            float x = Qs[r * LSTR + c];
            Qs[r * LSTR + c] = ((x - mu) * rsig * q_gamma[c] + q_beta[c]) * scale;
        }
    }

    // ---- online softmax state ----
    float m = -1e30f;
    float l = 0.f;
    float O[16];
    for (int i = 0; i < 16; ++i) O[i] = 0.f;

    for (int s0 = 0; s0 < TCTX; s0 += BK) {
        __syncthreads();  // previous tile's PV reads done before overwrite

        // ---- load K and V tiles ----
        for (int i = 0; i < 16; ++i) {
            int idx = tid + i * 256;
            int rr = idx >> 6, cc = idx & 63;
            size_t base = (size_t)(s0 + rr) * W3 + h * 192 + cc;
            Ks[rr * LSTR + cc] = qkv[base + 64];
            Vs[rr * LSTR + cc] = qkv[base + 128];
        }
        __syncthreads();

        // ---- LayerNorm K rows ----
        {
            float s = 0.f, s2 = 0.f;
            for (int i = 0; i < 16; ++i) {
                float x = Ks[r * LSTR + j * 16 + i];
                s += x; s2 += x * x;
            }
            s  += __shfl_xor(s, 1);  s  += __shfl_xor(s, 2);
            s2 += __shfl_xor(s2, 1); s2 += __shfl_xor(s2, 2);
            float mu   = s * (1.f / 64.f);
            float var  = s2 * (1.f / 64.f) - mu * mu;
            float rsig = rsqrtf(var + 1e-6f);
            for (int i = 0; i < 16; ++i) {
                int c = j * 16 + i;
                float x = Ks[r * LSTR + c];
                Ks[r * LSTR + c] = ((x - mu) * rsig * k_gamma[c] + k_beta[c]) * scale;
            }
        }
        __syncthreads();

        // ---- S = Q K^T : thread computes 16 columns of its q-row ----
        float sv[16];
        for (int i = 0; i < 16; ++i) {
            int s = j * 16 + i;
            float acc = 0.f;
            for (int k = 0; k < 64; ++k)
                acc = fmaf(Qs[r * LSTR + k], Ks[s * LSTR + k], acc);
            sv[i] = acc;
        }

        // ---- online softmax update ----
        float tmax = sv[0];
        for (int i = 1; i < 16; ++i) tmax = fmaxf(tmax, sv[i]);
        tmax = fmaxf(tmax, __shfl_xor(tmax, 1));
        tmax = fmaxf(tmax, __shfl_xor(tmax, 2));
        float new_m = fmaxf(m, tmax);
        float alpha = __expf(m - new_m);
        float psum = 0.f;
        for (int i = 0; i < 16; ++i) {
            float p = __expf(sv[i] - new_m);
            Ps[r * LSTR + j * 16 + i] = p;
            psum += p;
        }
        psum += __shfl_xor(psum, 1);
        psum += __shfl_xor(psum, 2);
        l = l * alpha + psum;
        m = new_m;
        for (int c = 0; c < 16; ++c) O[c] *= alpha;
        __syncthreads();  // P visible to all lanes of the row's PV

        // ---- O += P V : thread accumulates channels j*16..j*16+15 ----
        for (int s = 0; s < 64; ++s) {
            float p = Ps[r * LSTR + s];
            const float* vrow = &Vs[s * LSTR + j * 16];
            for (int cc = 0; cc < 16; ++cc)
                O[cc] = fmaf(p, vrow[cc], O[cc]);
        }
    }

    // ---- epilogue: normalize and store ----
    float inv_l = 1.f / l;
    size_t obase = (size_t)(q0 + r) * (HEADS * CH) + h * CH + j * 16;
    for (int cc = 0; cc < 16; ++cc)
        out[obase + cc] = O[cc] * inv_l;
}

extern "C" void kernel_launch(void* const* d_in, const int* in_sizes, int n_in,
                              void* d_out, int out_size, void* d_ws, size_t ws_size,
                              hipStream_t stream) {
    const float* qkv     = (const float*)d_in[0];
    const float* q_gamma = (const float*)d_in[1];
    const float* q_beta  = (const float*)d_in[2];
    const float* k_gamma = (const float*)d_in[3];
    const float* k_beta  = (const float*)d_in[4];
    float* out = (float*)d_out;

    dim3 grid(TCTX / BQ, HEADS);
    attn_fused_kernel<<<grid, 256, 0, stream>>>(qkv, q_gamma, q_beta,
                                                k_gamma, k_beta, out);
}

// Round 6
// 2258.362 us; speedup vs baseline: 1.4911x; 1.4911x over previous
//
#include <hip/hip_runtime.h>
#include <math.h>

#define TCTX 4096
#define HEADS 16
#define W3 3072
#define BQ 64
#define BK 64
#define LSTR 65   // float LDS row stride (R1's proven layout)
#define HSTR 72   // short LDS row stride for hi/lo arrays (144B rows, 16B aligned)

typedef short bf16x8 __attribute__((ext_vector_type(8)));
typedef float f32x4 __attribute__((ext_vector_type(4)));

static __device__ __forceinline__ unsigned short f2bf(float x) {
    union { float f; unsigned int u; } v; v.f = x;
    unsigned int r = v.u + 0x7fffu + ((v.u >> 16) & 1u);  // RNE
    return (unsigned short)(r >> 16);
}
static __device__ __forceinline__ float bf2f(unsigned short h) {
    union { float f; unsigned int u; } v; v.u = ((unsigned int)h) << 16;
    return v.f;
}
#define PK2(a,b) ((unsigned int)(a) | ((unsigned int)(b) << 16))

// R6 BISECTION: R1's passing kernel VERBATIM except S = QK^T comes from the
// split-precision bf16 MFMA path (hi/lo convert -> fragment reads -> MFMA ->
// C-layout scatter to LDS fp32). Softmax/PV/epilogue untouched R1 code.
__global__ __launch_bounds__(256, 1) void attn_bisect2_kernel(
    const float* __restrict__ qkv,
    const float* __restrict__ q_gamma, const float* __restrict__ q_beta,
    const float* __restrict__ k_gamma, const float* __restrict__ k_beta,
    float* __restrict__ out)
{
    __shared__ float Qs[BQ * LSTR];
    __shared__ float Ks[BK * LSTR];
    __shared__ float Vs[BK * LSTR];
    __shared__ float Ss[BQ * LSTR];          // S tile (fp32), then P in-place
    __shared__ unsigned short Qh[BQ * HSTR], Ql[BQ * HSTR];
    __shared__ unsigned short Kh[BK * HSTR], Kl[BK * HSTR];

    const int tid  = threadIdx.x;
    const int h    = blockIdx.y;
    const int q0   = blockIdx.x * BQ;
    const int lane = tid & 63;
    const int wv   = tid >> 6;
    const int l15  = lane & 15;
    const int quad = lane >> 4;
    const int m0   = wv * 16;
    const int r    = tid >> 2;
    const int j    = tid & 3;

    const float scale = 0.35355339059327373f;  // 64^(-1/4)

    // ---- stage Q tile (R1 verbatim) ----
    for (int i = 0; i < 16; ++i) {
        int idx = tid + i * 256;
        int rr = idx >> 6, cc = idx & 63;
        Qs[rr * LSTR + cc] = qkv[(size_t)(q0 + rr) * W3 + h * 192 + cc];
    }
    __syncthreads();

    // ---- LayerNorm Q rows (R1 verbatim) + INSERT hi/lo emit ----
    {
        float s = 0.f, s2 = 0.f;
        for (int i = 0; i < 16; ++i) {
            float x = Qs[r * LSTR + j * 16 + i];
            s += x; s2 += x * x;
        }
        s  += __shfl_xor(s, 1);  s  += __shfl_xor(s, 2);
        s2 += __shfl_xor(s2, 1); s2 += __shfl_xor(s2, 2);
        float mu   = s * (1.f / 64.f);
        float var  = s2 * (1.f / 64.f) - mu * mu;
        float rsig = rsqrtf(var + 1e-6f);
        unsigned short hi[16], lo[16];
        for (int i = 0; i < 16; ++i) {
            int c = j * 16 + i;
            float x = Qs[r * LSTR + c];
            float y = ((x - mu) * rsig * q_gamma[c] + q_beta[c]) * scale;
            Qs[r * LSTR + c] = y;
            unsigned short yh = f2bf(y);
            hi[i] = yh;
            lo[i] = f2bf(y - bf2f(yh));
        }
        uint4* dh = (uint4*)(Qh + r * HSTR + j * 16);
        dh[0] = make_uint4(PK2(hi[0],hi[1]), PK2(hi[2],hi[3]), PK2(hi[4],hi[5]), PK2(hi[6],hi[7]));
        dh[1] = make_uint4(PK2(hi[8],hi[9]), PK2(hi[10],hi[11]), PK2(hi[12],hi[13]), PK2(hi[14],hi[15]));
        uint4* dl = (uint4*)(Ql + r * HSTR + j * 16);
        dl[0] = make_uint4(PK2(lo[0],lo[1]), PK2(lo[2],lo[3]), PK2(lo[4],lo[5]), PK2(lo[6],lo[7]));
        dl[1] = make_uint4(PK2(lo[8],lo[9]), PK2(lo[10],lo[11]), PK2(lo[12],lo[13]), PK2(lo[14],lo[15]));
    }
    __syncthreads();

    // hoist Q fragments (A[m=lane&15][k=quad*8+j]) — Qh/Ql final, barrier above
    bf16x8 qh0 = *(const bf16x8*)(Qh + (m0 + l15) * HSTR +      quad * 8);
    bf16x8 qh1 = *(const bf16x8*)(Qh + (m0 + l15) * HSTR + 32 + quad * 8);
    bf16x8 ql0 = *(const bf16x8*)(Ql + (m0 + l15) * HSTR +      quad * 8);
    bf16x8 ql1 = *(const bf16x8*)(Ql + (m0 + l15) * HSTR + 32 + quad * 8);

    // ---- online softmax state (R1 verbatim) ----
    float m = -1e30f;
    float l = 0.f;
    float O[16];
    for (int i = 0; i < 16; ++i) O[i] = 0.f;

    for (int s0 = 0; s0 < TCTX; s0 += BK) {
        __syncthreads();  // previous tile's PV reads done before overwrite

        // ---- load K and V tiles (R1 verbatim) ----
        for (int i = 0; i < 16; ++i) {
            int idx = tid + i * 256;
            int rr = idx >> 6, cc = idx & 63;
            size_t base = (size_t)(s0 + rr) * W3 + h * 192 + cc;
            Ks[rr * LSTR + cc] = qkv[base + 64];
            Vs[rr * LSTR + cc] = qkv[base + 128];
        }
        __syncthreads();

        // ---- LayerNorm K rows (R1 verbatim) + INSERT hi/lo emit ----
        {
            float s = 0.f, s2 = 0.f;
            for (int i = 0; i < 16; ++i) {
                float x = Ks[r * LSTR + j * 16 + i];
                s += x; s2 += x * x;
            }
            s  += __shfl_xor(s, 1);  s  += __shfl_xor(s, 2);
            s2 += __shfl_xor(s2, 1); s2 += __shfl_xor(s2, 2);
            float mu   = s * (1.f / 64.f);
            float var  = s2 * (1.f / 64.f) - mu * mu;
            float rsig = rsqrtf(var + 1e-6f);
            unsigned short hi[16], lo[16];
            for (int i = 0; i < 16; ++i) {
                int c = j * 16 + i;
                float x = Ks[r * LSTR + c];
                float y = ((x - mu) * rsig * k_gamma[c] + k_beta[c]) * scale;
                Ks[r * LSTR + c] = y;
                unsigned short yh = f2bf(y);
                hi[i] = yh;
                lo[i] = f2bf(y - bf2f(yh));
            }
            uint4* dh = (uint4*)(Kh + r * HSTR + j * 16);
            dh[0] = make_uint4(PK2(hi[0],hi[1]), PK2(hi[2],hi[3]), PK2(hi[4],hi[5]), PK2(hi[6],hi[7]));
            dh[1] = make_uint4(PK2(hi[8],hi[9]), PK2(hi[10],hi[11]), PK2(hi[12],hi[13]), PK2(hi[14],hi[15]));
            uint4* dl = (uint4*)(Kl + r * HSTR + j * 16);
            dl[0] = make_uint4(PK2(lo[0],lo[1]), PK2(lo[2],lo[3]), PK2(lo[4],lo[5]), PK2(lo[6],lo[7]));
            dl[1] = make_uint4(PK2(lo[8],lo[9]), PK2(lo[10],lo[11]), PK2(lo[12],lo[13]), PK2(lo[14],lo[15]));
        }
        __syncthreads();

        // ---- INSERT: S = Q K^T via split MFMA, scatter C-layout -> Ss fp32 ----
        {
            f32x4 accs[4];
            #pragma unroll
            for (int t = 0; t < 4; ++t) accs[t] = (f32x4){0.f, 0.f, 0.f, 0.f};
            #pragma unroll
            for (int s = 0; s < 2; ++s) {
                bf16x8 qh = s ? qh1 : qh0;
                bf16x8 ql = s ? ql1 : ql0;
                #pragma unroll
                for (int t = 0; t < 4; ++t) {
                    bf16x8 kh = *(const bf16x8*)(Kh + (t*16 + l15) * HSTR + s*32 + quad*8);
                    bf16x8 kl = *(const bf16x8*)(Kl + (t*16 + l15) * HSTR + s*32 + quad*8);
                    accs[t] = __builtin_amdgcn_mfma_f32_16x16x32_bf16(ql, kh, accs[t], 0, 0, 0);
                    accs[t] = __builtin_amdgcn_mfma_f32_16x16x32_bf16(qh, kl, accs[t], 0, 0, 0);
                    accs[t] = __builtin_amdgcn_mfma_f32_16x16x32_bf16(qh, kh, accs[t], 0, 0, 0);
                }
            }
            #pragma unroll
            for (int t = 0; t < 4; ++t)
                #pragma unroll
                for (int i = 0; i < 4; ++i)
                    Ss[(m0 + quad*4 + i) * LSTR + t*16 + l15] = accs[t][i];
        }
        __syncthreads();

        // ---- R1 softmax, reading S from Ss instead of dot products ----
        float sv[16];
        for (int i = 0; i < 16; ++i)
            sv[i] = Ss[r * LSTR + j * 16 + i];

        float tmax = sv[0];
        for (int i = 1; i < 16; ++i) tmax = fmaxf(tmax, sv[i]);
        tmax = fmaxf(tmax, __shfl_xor(tmax, 1));
        tmax = fmaxf(tmax, __shfl_xor(tmax, 2));
        float new_m = fmaxf(m, tmax);
        float alpha = __expf(m - new_m);
        float psum = 0.f;
        for (int i = 0; i < 16; ++i) {
            float p = __expf(sv[i] - new_m);
            Ss[r * LSTR + j * 16 + i] = p;   // P in-place (own slots)
            psum += p;
        }
        psum += __shfl_xor(psum, 1);
        psum += __shfl_xor(psum, 2);
        l = l * alpha + psum;
        m = new_m;
        for (int c = 0; c < 16; ++c) O[c] *= alpha;
        __syncthreads();  // P visible to all lanes of the row's PV

        // ---- O += P V (R1 verbatim) ----
        for (int s = 0; s < 64; ++s) {
            float p = Ss[r * LSTR + s];
            const float* vrow = &Vs[s * LSTR + j * 16];
            for (int cc = 0; cc < 16; ++cc)
                O[cc] = fmaf(p, vrow[cc], O[cc]);
        }
    }

    // ---- epilogue (R1 verbatim) ----
    float inv_l = 1.f / l;
    size_t obase = (size_t)(q0 + r) * (HEADS * 64) + h * 64 + j * 16;
    for (int cc = 0; cc < 16; ++cc)
        out[obase + cc] = O[cc] * inv_l;
}

extern "C" void kernel_launch(void* const* d_in, const int* in_sizes, int n_in,
                              void* d_out, int out_size, void* d_ws, size_t ws_size,
                              hipStream_t stream) {
    const float* qkv     = (const float*)d_in[0];
    const float* q_gamma = (const float*)d_in[1];
    const float* q_beta  = (const float*)d_in[2];
    const float* k_gamma = (const float*)d_in[3];
    const float* k_beta  = (const float*)d_in[4];
    float* out = (float*)d_out;

    dim3 grid(TCTX / BQ, HEADS);
    attn_bisect2_kernel<<<grid, 256, 0, stream>>>(qkv, q_gamma, q_beta,
                                                  k_gamma, k_beta, out);
}

// Round 7
// 1482.681 us; speedup vs baseline: 2.2712x; 1.5232x over previous
//
#include <hip/hip_runtime.h>
#include <math.h>

#define TCTX 4096
#define HEADS 16
#define W3 3072
#define BQ 64
#define BK 64
#define LSTR 65   // float LDS row stride (proven R1/R6 layout)
#define HSTR 72   // short LDS row stride (144B rows, 16B aligned)

typedef short bf16x8 __attribute__((ext_vector_type(8)));
typedef float f32x4 __attribute__((ext_vector_type(4)));

static __device__ __forceinline__ unsigned short f2bf(float x) {
    union { float f; unsigned int u; } v; v.f = x;
    unsigned int r = v.u + 0x7fffu + ((v.u >> 16) & 1u);  // RNE
    return (unsigned short)(r >> 16);
}
static __device__ __forceinline__ float bf2f(unsigned short h) {
    union { float f; unsigned int u; } v; v.u = ((unsigned int)h) << 16;
    return v.f;
}
#define PK2(a,b) ((unsigned int)(a) | ((unsigned int)(b) << 16))

// R7: R6 (proven) + MFMA PV. QK^T: split bf16 MFMA -> Ss scatter (proven).
// Softmax: (r,j) layout (proven). NEW: P -> hi/lo Ph/Pl, V staged transposed
// hi/lo, PV via 3-MFMA split, O in C-layout, alpha/l broadcast via LDS.
__global__ __launch_bounds__(256, 1) void attn_r7_kernel(
    const float* __restrict__ qkv,
    const float* __restrict__ q_gamma, const float* __restrict__ q_beta,
    const float* __restrict__ k_gamma, const float* __restrict__ k_beta,
    float* __restrict__ out)
{
    __shared__ float Qs[BQ * LSTR];
    __shared__ float Ks[BK * LSTR];
    __shared__ float Ss[BQ * LSTR];          // S scatter (fp32)
    __shared__ unsigned short Qh[BQ * HSTR], Ql[BQ * HSTR];
    __shared__ unsigned short Kh[BK * HSTR], Kl[BK * HSTR];
    __shared__ unsigned short Vth[64 * HSTR], Vtl[64 * HSTR];  // [ch][key]
    __shared__ unsigned short Ph[BQ * HSTR], Pl[BQ * HSTR];    // [row][key]
    __shared__ float axs[BQ];   // per-row alpha (thread layout -> C layout)
    __shared__ float lin[BQ];   // per-row 1/l

    const int tid  = threadIdx.x;
    const int h    = blockIdx.y;
    const int q0   = blockIdx.x * BQ;
    const int lane = tid & 63;
    const int wv   = tid >> 6;
    const int l15  = lane & 15;
    const int quad = lane >> 4;
    const int m0   = wv * 16;
    const int r    = tid >> 2;
    const int j    = tid & 3;

    const float scale = 0.35355339059327373f;  // 64^(-1/4)

    // ---- stage Q tile (R6 verbatim) ----
    for (int i = 0; i < 16; ++i) {
        int idx = tid + i * 256;
        int rr = idx >> 6, cc = idx & 63;
        Qs[rr * LSTR + cc] = qkv[(size_t)(q0 + rr) * W3 + h * 192 + cc];
    }
    __syncthreads();

    // ---- LayerNorm Q rows + hi/lo emit (R6, dead Qs write-back dropped) ----
    {
        float s = 0.f, s2 = 0.f;
        for (int i = 0; i < 16; ++i) {
            float x = Qs[r * LSTR + j * 16 + i];
            s += x; s2 += x * x;
        }
        s  += __shfl_xor(s, 1);  s  += __shfl_xor(s, 2);
        s2 += __shfl_xor(s2, 1); s2 += __shfl_xor(s2, 2);
        float mu   = s * (1.f / 64.f);
        float var  = s2 * (1.f / 64.f) - mu * mu;
        float rsig = rsqrtf(var + 1e-6f);
        unsigned short hi[16], lo[16];
        for (int i = 0; i < 16; ++i) {
            int c = j * 16 + i;
            float x = Qs[r * LSTR + c];
            float y = ((x - mu) * rsig * q_gamma[c] + q_beta[c]) * scale;
            unsigned short yh = f2bf(y);
            hi[i] = yh;
            lo[i] = f2bf(y - bf2f(yh));
        }
        uint4* dh = (uint4*)(Qh + r * HSTR + j * 16);
        dh[0] = make_uint4(PK2(hi[0],hi[1]), PK2(hi[2],hi[3]), PK2(hi[4],hi[5]), PK2(hi[6],hi[7]));
        dh[1] = make_uint4(PK2(hi[8],hi[9]), PK2(hi[10],hi[11]), PK2(hi[12],hi[13]), PK2(hi[14],hi[15]));
        uint4* dl = (uint4*)(Ql + r * HSTR + j * 16);
        dl[0] = make_uint4(PK2(lo[0],lo[1]), PK2(lo[2],lo[3]), PK2(lo[4],lo[5]), PK2(lo[6],lo[7]));
        dl[1] = make_uint4(PK2(lo[8],lo[9]), PK2(lo[10],lo[11]), PK2(lo[12],lo[13]), PK2(lo[14],lo[15]));
    }
    __syncthreads();

    // hoist Q fragments (A[m=lane&15][k=quad*8+j]) — Qh/Ql LDS dead afterwards
    bf16x8 qh0 = *(const bf16x8*)(Qh + (m0 + l15) * HSTR +      quad * 8);
    bf16x8 qh1 = *(const bf16x8*)(Qh + (m0 + l15) * HSTR + 32 + quad * 8);
    bf16x8 ql0 = *(const bf16x8*)(Ql + (m0 + l15) * HSTR +      quad * 8);
    bf16x8 ql1 = *(const bf16x8*)(Ql + (m0 + l15) * HSTR + 32 + quad * 8);

    // softmax state per thread (r,j); O accumulator in MFMA C-layout per lane
    float m = -1e30f;
    float l = 0.f;
    f32x4 acco[4];
    #pragma unroll
    for (int t = 0; t < 4; ++t) acco[t] = (f32x4){0.f, 0.f, 0.f, 0.f};

    for (int s0 = 0; s0 < TCTX; s0 += BK) {
        __syncthreads();  // prior tile's Kh/Kl/Vth/Vtl/Ph/Pl/Ss reads complete

        // ---- stage K -> Ks fp32 (R6 loader, K only) ----
        for (int i = 0; i < 16; ++i) {
            int idx = tid + i * 256;
            int rr = idx >> 6, cc = idx & 63;
            Ks[rr * LSTR + cc] = qkv[(size_t)(s0 + rr) * W3 + h * 192 + 64 + cc];
        }
        // ---- stage V transposed hi/lo: Vth/Vtl[ch][key] ----
        {
            const float4* src = (const float4*)(qkv + (size_t)(s0 + r) * W3 + h * 192 + 128 + j * 16);
            #pragma unroll
            for (int c = 0; c < 4; ++c) {
                float4 v4 = src[c];
                float vv[4] = {v4.x, v4.y, v4.z, v4.w};
                #pragma unroll
                for (int k = 0; k < 4; ++k) {
                    unsigned short vh = f2bf(vv[k]);
                    Vth[(j*16 + 4*c + k) * HSTR + r] = vh;
                    Vtl[(j*16 + 4*c + k) * HSTR + r] = f2bf(vv[k] - bf2f(vh));
                }
            }
        }
        __syncthreads();

        // ---- LayerNorm K rows + hi/lo emit (R6, dead Ks write-back dropped) ----
        {
            float s = 0.f, s2 = 0.f;
            for (int i = 0; i < 16; ++i) {
                float x = Ks[r * LSTR + j * 16 + i];
                s += x; s2 += x * x;
            }
            s  += __shfl_xor(s, 1);  s  += __shfl_xor(s, 2);
            s2 += __shfl_xor(s2, 1); s2 += __shfl_xor(s2, 2);
            float mu   = s * (1.f / 64.f);
            float var  = s2 * (1.f / 64.f) - mu * mu;
            float rsig = rsqrtf(var + 1e-6f);
            unsigned short hi[16], lo[16];
            for (int i = 0; i < 16; ++i) {
                int c = j * 16 + i;
                float x = Ks[r * LSTR + c];
                float y = ((x - mu) * rsig * k_gamma[c] + k_beta[c]) * scale;
                unsigned short yh = f2bf(y);
                hi[i] = yh;
                lo[i] = f2bf(y - bf2f(yh));
            }
            uint4* dh = (uint4*)(Kh + r * HSTR + j * 16);
            dh[0] = make_uint4(PK2(hi[0],hi[1]), PK2(hi[2],hi[3]), PK2(hi[4],hi[5]), PK2(hi[6],hi[7]));
            dh[1] = make_uint4(PK2(hi[8],hi[9]), PK2(hi[10],hi[11]), PK2(hi[12],hi[13]), PK2(hi[14],hi[15]));
            uint4* dl = (uint4*)(Kl + r * HSTR + j * 16);
            dl[0] = make_uint4(PK2(lo[0],lo[1]), PK2(lo[2],lo[3]), PK2(lo[4],lo[5]), PK2(lo[6],lo[7]));
            dl[1] = make_uint4(PK2(lo[8],lo[9]), PK2(lo[10],lo[11]), PK2(lo[12],lo[13]), PK2(lo[14],lo[15]));
        }
        __syncthreads();

        // ---- S = Q K^T via split MFMA, scatter C-layout -> Ss fp32 (R6 verbatim) ----
        {
            f32x4 accs[4];
            #pragma unroll
            for (int t = 0; t < 4; ++t) accs[t] = (f32x4){0.f, 0.f, 0.f, 0.f};
            #pragma unroll
            for (int s = 0; s < 2; ++s) {
                bf16x8 qh = s ? qh1 : qh0;
                bf16x8 ql = s ? ql1 : ql0;
                #pragma unroll
                for (int t = 0; t < 4; ++t) {
                    bf16x8 kh = *(const bf16x8*)(Kh + (t*16 + l15) * HSTR + s*32 + quad*8);
                    bf16x8 kl = *(const bf16x8*)(Kl + (t*16 + l15) * HSTR + s*32 + quad*8);
                    accs[t] = __builtin_amdgcn_mfma_f32_16x16x32_bf16(ql, kh, accs[t], 0, 0, 0);
                    accs[t] = __builtin_amdgcn_mfma_f32_16x16x32_bf16(qh, kl, accs[t], 0, 0, 0);
                    accs[t] = __builtin_amdgcn_mfma_f32_16x16x32_bf16(qh, kh, accs[t], 0, 0, 0);
                }
            }
            #pragma unroll
            for (int t = 0; t < 4; ++t)
                #pragma unroll
                for (int i = 0; i < 4; ++i)
                    Ss[(m0 + quad*4 + i) * LSTR + t*16 + l15] = accs[t][i];
        }
        __syncthreads();

        // ---- softmax in (r,j) layout (R6 logic); NEW: emit Ph/Pl + axs ----
        {
            float sv[16];
            for (int i = 0; i < 16; ++i)
                sv[i] = Ss[r * LSTR + j * 16 + i];

            float tmax = sv[0];
            for (int i = 1; i < 16; ++i) tmax = fmaxf(tmax, sv[i]);
            tmax = fmaxf(tmax, __shfl_xor(tmax, 1));
            tmax = fmaxf(tmax, __shfl_xor(tmax, 2));
            float new_m = fmaxf(m, tmax);
            float alpha = __expf(m - new_m);
            float psum = 0.f;
            unsigned short hi[16], lo[16];
            for (int i = 0; i < 16; ++i) {
                float p = __expf(sv[i] - new_m);
                psum += p;
                unsigned short ph = f2bf(p);
                hi[i] = ph;
                lo[i] = f2bf(p - bf2f(ph));
            }
            psum += __shfl_xor(psum, 1);
            psum += __shfl_xor(psum, 2);
            l = l * alpha + psum;
            m = new_m;
            uint4* dh = (uint4*)(Ph + r * HSTR + j * 16);
            dh[0] = make_uint4(PK2(hi[0],hi[1]), PK2(hi[2],hi[3]), PK2(hi[4],hi[5]), PK2(hi[6],hi[7]));
            dh[1] = make_uint4(PK2(hi[8],hi[9]), PK2(hi[10],hi[11]), PK2(hi[12],hi[13]), PK2(hi[14],hi[15]));
            uint4* dl = (uint4*)(Pl + r * HSTR + j * 16);
            dl[0] = make_uint4(PK2(lo[0],lo[1]), PK2(lo[2],lo[3]), PK2(lo[4],lo[5]), PK2(lo[6],lo[7]));
            dl[1] = make_uint4(PK2(lo[8],lo[9]), PK2(lo[10],lo[11]), PK2(lo[12],lo[13]), PK2(lo[14],lo[15]));
            if (j == 0) axs[r] = alpha;
        }
        __syncthreads();  // Ph/Pl + axs visible

        // ---- rescale O (C-layout rows m0+quad*4+i) ----
        {
            float af[4];
            #pragma unroll
            for (int i = 0; i < 4; ++i) af[i] = axs[m0 + quad*4 + i];
            #pragma unroll
            for (int t = 0; t < 4; ++t)
                #pragma unroll
                for (int i = 0; i < 4; ++i)
                    acco[t][i] *= af[i];
        }

        // ---- O += P V via split MFMA (A path ≡ proven Q path, B ≡ proven K path) ----
        #pragma unroll
        for (int s = 0; s < 2; ++s) {
            bf16x8 pa_h = *(const bf16x8*)(Ph + (m0 + l15) * HSTR + s*32 + quad*8);
            bf16x8 pa_l = *(const bf16x8*)(Pl + (m0 + l15) * HSTR + s*32 + quad*8);
            #pragma unroll
            for (int t = 0; t < 4; ++t) {
                bf16x8 vb_h = *(const bf16x8*)(Vth + (t*16 + l15) * HSTR + s*32 + quad*8);
                bf16x8 vb_l = *(const bf16x8*)(Vtl + (t*16 + l15) * HSTR + s*32 + quad*8);
                acco[t] = __builtin_amdgcn_mfma_f32_16x16x32_bf16(pa_l, vb_h, acco[t], 0, 0, 0);
                acco[t] = __builtin_amdgcn_mfma_f32_16x16x32_bf16(pa_h, vb_l, acco[t], 0, 0, 0);
                acco[t] = __builtin_amdgcn_mfma_f32_16x16x32_bf16(pa_h, vb_h, acco[t], 0, 0, 0);
            }
        }
    }

    // ---- epilogue: 1/l broadcast, normalize, C-layout store (proven mapping) ----
    if (j == 0) lin[r] = 1.f / l;
    __syncthreads();
    {
        float il[4];
        #pragma unroll
        for (int i = 0; i < 4; ++i) il[i] = lin[m0 + quad*4 + i];
        #pragma unroll
        for (int i = 0; i < 4; ++i) {
            const int row = q0 + m0 + quad*4 + i;
            float* op = out + (size_t)row * (HEADS * 64) + h * 64 + l15;
            #pragma unroll
            for (int t = 0; t < 4; ++t)
                op[t * 16] = acco[t][i] * il[i];
        }
    }
}

extern "C" void kernel_launch(void* const* d_in, const int* in_sizes, int n_in,
                              void* d_out, int out_size, void* d_ws, size_t ws_size,
                              hipStream_t stream) {
    const float* qkv     = (const float*)d_in[0];
    const float* q_gamma = (const float*)d_in[1];
    const float* q_beta  = (const float*)d_in[2];
    const float* k_gamma = (const float*)d_in[3];
    const float* k_beta  = (const float*)d_in[4];
    float* out = (float*)d_out;

    dim3 grid(TCTX / BQ, HEADS);
    attn_r7_kernel<<<grid, 256, 0, stream>>>(qkv, q_gamma, q_beta,
                                             k_gamma, k_beta, out);
}